// Round 17
// baseline (120.767 us; speedup 1.0000x reference)
//
#include <hip/hip_runtime.h>
#include <hip/hip_bf16.h>

#define NROW 8192
#define NDIM 256
#define INV_T (1.0f / 0.07f)
#define K_BOT 819      // first selected descending rank
#define K_TOP 4095     // one past last selected rank
#define N_SEL 3276
#define N_UNSEL 4916   // 8192 - N_SEL (includes diagonal at -10)

typedef unsigned int u32;
typedef unsigned short u16;
typedef short s16;
typedef unsigned long long u64;
typedef __bf16 bf16_t;
typedef s16 s16x8 __attribute__((ext_vector_type(8)));
typedef float f32x4 __attribute__((ext_vector_type(4)));

__device__ __forceinline__ u16 bfbits(float f) {
    return __builtin_bit_cast(u16, (bf16_t)f);   // RNE f32->bf16, raw bits
}
// order-preserving bf16-bits -> u16 key (bigger float <=> bigger key)
__device__ __forceinline__ u16 map16(u16 b) {
    return (b & 0x8000u) ? (u16)~b : (u16)(b | 0x8000u);
}
__device__ __forceinline__ float unmap16(u32 m) {
    u16 b = (m & 0x8000u) ? (u16)(m & 0x7FFFu) : (u16)~(u16)m;
    return __uint_as_float(((u32)b) << 16);
}

__device__ __forceinline__ void gload16(const void* g, void* l) {
    __builtin_amdgcn_global_load_lds(
        (const __attribute__((address_space(1))) u32*)g,
        (__attribute__((address_space(3))) u32*)l, 16, 0, 0);
}

// ---------------- fp32 -> bf16 (both inputs, one launch) ----------------
__global__ __launch_bounds__(256) void cvt_bf16(const float* __restrict__ in0,
                                                const float* __restrict__ in1,
                                                u16* __restrict__ out0,
                                                u16* __restrict__ out1) {
    int b = blockIdx.x;
    const float* in = (b < 2048) ? in0 : in1;
    u16* out = (b < 2048) ? out0 : out1;
    int i = ((b & 2047) * 256 + threadIdx.x) * 4;
    float4 v = *(const float4*)(in + i);
    ushort4 o;
    o.x = bfbits(v.x); o.y = bfbits(v.y); o.z = bfbits(v.z); o.w = bfbits(v.w);
    *(ushort4*)(out + i) = o;
}

// ---------------- GEMM: keys = map16(bf16(Q @ K^T)) ----------------
// 128x128 tile, BK=64, 8 waves (512 thr), wave tile 64x32 (acc 32 regs).
// Proven round-14 form. No min-waves launch_bounds (round-13 spill lesson).
__global__ __launch_bounds__(512) void gemm_keys(const u16* __restrict__ Qb,
                                                 const u16* __restrict__ Kb,
                                                 u16* __restrict__ Cp) {
    constexpr int BK = 64;
    __shared__ __align__(16) char smem[128 * 132 * 2];   // 33792 B (union)
    u16* sA = (u16*)smem;                    // [128][64] bf16 (16 KB)
    u16* sB = (u16*)(smem + 128 * BK * 2);   // [128][64] (16 KB)
    u16* sC = (u16*)smem;                    // [128][132] epilogue transpose

    const int tid  = threadIdx.x;
    const int lane = tid & 63;
    const int wid  = tid >> 6;               // 0..7
    const int wr = wid & 1;                  // row half   (64 rows)
    const int wc = wid >> 1;                 // col quarter (32 cols)
    const int bm = blockIdx.y * 128;
    const int bn = blockIdx.x * 128;
    const int kg = lane >> 4;
    const int fr = lane & 15;

    // staging: segment = 8 rows x 128B; lane l -> row seg*8 + (l>>3),
    // LDS chunk jp = l&7 holds source chunk j = jp ^ (row&7).
    const int srr = lane >> 3;
    const int srj = (lane & 7) ^ srr;

    f32x4 acc[4][2] = {};

    for (int k0 = 0; k0 < NDIM; k0 += BK) {
        __syncthreads();
#pragma unroll
        for (int s = 0; s < 2; ++s) {
            int seg = wid * 2 + s;               // 0..15
            int row = seg * 8 + srr;
            gload16(Qb + (size_t)(bm + row) * NDIM + k0 + srj * 8, &sA[seg * 512]);
            gload16(Kb + (size_t)(bn + row) * NDIM + k0 + srj * 8, &sB[seg * 512]);
        }
        __syncthreads();

#pragma unroll
        for (int kk = 0; kk < 2; ++kk) {
            s16x8 af[4], bfv[2];
            const int jp = (kk * 4 + kg) ^ (fr & 7);   // row&7 == fr&7 below
#pragma unroll
            for (int m = 0; m < 4; ++m) {
                int row = wr * 64 + m * 16 + fr;
                af[m] = *(const s16x8*)(&sA[row * BK + jp * 8]);
            }
#pragma unroll
            for (int n = 0; n < 2; ++n) {
                int row = wc * 32 + n * 16 + fr;
                bfv[n] = *(const s16x8*)(&sB[row * BK + jp * 8]);
            }
#pragma unroll
            for (int m = 0; m < 4; ++m)
#pragma unroll
                for (int n = 0; n < 2; ++n)
                    acc[m][n] = __builtin_amdgcn_mfma_f32_16x16x32_bf16(
                        af[m], bfv[n], acc[m][n], 0, 0, 0);
        }
    }

    __syncthreads();   // done reading sA/sB; reuse LDS as sC
#pragma unroll
    for (int m = 0; m < 4; ++m)
#pragma unroll
        for (int n = 0; n < 2; ++n)
#pragma unroll
            for (int jj = 0; jj < 4; ++jj) {
                int r = wr * 64 + m * 16 + kg * 4 + jj;   // C/D: row=(lane>>4)*4+reg
                int c = wc * 32 + n * 16 + fr;            //      col=lane&15
                sC[r * 132 + c] = map16(bfbits(acc[m][n][jj]));
            }
    __syncthreads();
    if (bm == bn) {
        if (tid < 128) sC[tid * 132 + tid] = 0;   // diagonal sentinel (unique min)
        __syncthreads();
    }
#pragma unroll
    for (int it = 0; it < 4; ++it) {
        int idx = it * 512 + tid;                 // 0..2047 16B chunks
        int row = idx >> 4, col8 = (idx & 15) * 8;
        *(uint4*)(&Cp[(size_t)(bm + row) * NROW + bn + col8]) =
            *(const uint4*)(&sC[row * 132 + col8]);
    }
}

// ---------------- rank select + LSE: 1 wave/row, 0 barriers, 2 sweeps -----
// resolve rank `rem` within a 128-key sub-hist (packed u16 counts, 64 words)
__device__ __forceinline__ void resolve_slot(const u32* sub, int slot, u32 rem,
                                             int lane, u32* idxOut, u32* gtOut) {
    u32 word = sub[slot * 64 + lane];
    u32 c0 = word & 0xFFFFu, c1 = word >> 16;     // idx 2*lane, 2*lane+1
    u32 s0 = c0 + c1, suf = s0;
#pragma unroll
    for (int o = 1; o < 64; o <<= 1) {
        u32 v = __shfl_down(suf, o);
        if (lane + o < 64) suf += v;
    }
    u32 TexL = suf - s0;                  // counts in higher lanes
    u32 f = 0, pk = 0;
    u32 ab0 = TexL + c1;                  // keys above idx 2*lane
    if (rem >= ab0 && rem < ab0 + c0) { f = 1; pk = ((u32)(lane * 2) << 16) | ab0; }
    if (rem >= TexL && rem < TexL + c1) { f = 1; pk = ((u32)(lane * 2 + 1) << 16) | TexL; }
    u64 mm = __ballot(f != 0);
    pk = __shfl(pk, (int)(__ffsll((unsigned long long)mm) - 1));
    *idxOut = pk >> 16;
    *gtOut = pk & 0xFFFFu;
}

// 128-thread blocks (2 independent waves). S1 hist: 4 interleaved copies
// (lane&3) of u16-packed counts. Round-17: unroll 8 sweeps (2x MLP; VGPR
// ~56 < 64 so 32 waves/CU preserved) + key-space S2 predicate.
__global__ __launch_bounds__(128, 8) void rank_lse(const u16* __restrict__ Cp,
                                                   const float* __restrict__ fq,
                                                   const float* __restrict__ fk,
                                                   float* __restrict__ loss) {
    __shared__ u32 lds_s[2][1056];        // 8448 B/block; per-wave private
    const int t = threadIdx.x;
    const int w = t >> 6;
    const int lane = t & 63;
    const int row = blockIdx.x * 2 + w;

    u32* W   = lds_s[w];                  // 4 copies x 264 words (u16-packed)
    u32* sub = W;                          // [0,512) S2 sub-hists (alias, hist dead)

    const uint4* rp = (const uint4*)(Cp + (size_t)row * NROW);

    // zero all 1056 hist words
    {
        const uint4 z = make_uint4(0, 0, 0, 0);
#pragma unroll
        for (int i = 0; i < 4; ++i) *(uint4*)&W[i * 256 + lane * 4] = z;
        if (lane < 8) *(uint4*)&W[1024 + lane * 4] = z;
    }

    // exact fp32 l_pos
    float lp;
    {
        float4 q4 = *(const float4*)(fq + (size_t)row * NDIM + lane * 4);
        float4 k4 = *(const float4*)(fk + (size_t)row * NDIM + lane * 4);
        float p = q4.x * k4.x + q4.y * k4.y + q4.z * k4.z + q4.w * k4.w;
#pragma unroll
        for (int o = 32; o; o >>= 1) p += __shfl_down(p, o);
        lp = __shfl(p, 0);
    }

    // ---- S1: 512-bin hist (key>>7), 4 interleaved u16-packed copies ----
    u32* const hc = &W[(lane & 3) * 264];
#pragma unroll 8
    for (int i = 0; i < 16; ++i) {
        uint4 v = rp[i * 64 + lane];
        u32 vv[4] = { v.x, v.y, v.z, v.w };
#pragma unroll
        for (int q = 0; q < 4; ++q) {
            u32 b0 = (vv[q] >> 7) & 0x1FFu;
            u32 b1 = vv[q] >> 23;
            atomicAdd(&hc[b0 & 255u], 1u << ((b0 & 0x100u) >> 4));
            atomicAdd(&hc[b1 & 255u], 1u << ((b1 & 0x100u) >> 4));
        }
    }

    // ---- merge copies + suffix scan (8 bins/lane over 512) ----
    u32 h[8], Wa[8];
    {
        u32 hx[8] = {0, 0, 0, 0, 0, 0, 0, 0};
        const int wbase = (lane & 31) * 8;
        const u32 hsh = (u32)(lane >> 5) * 16;   // low/high half select
#pragma unroll
        for (int c = 0; c < 4; ++c) {
            uint4 w0 = *(const uint4*)&W[c * 264 + wbase];
            uint4 w1 = *(const uint4*)&W[c * 264 + wbase + 4];
            u32 ws[8] = { w0.x, w0.y, w0.z, w0.w, w1.x, w1.y, w1.z, w1.w };
#pragma unroll
            for (int j = 0; j < 8; ++j) hx[j] += (ws[j] >> hsh) & 0xFFFFu;
        }
#pragma unroll
        for (int j = 0; j < 8; ++j) h[j] = hx[j];
    }
    Wa[7] = 0;
#pragma unroll
    for (int j = 6; j >= 0; --j) Wa[j] = Wa[j + 1] + h[j + 1];
    u32 P = Wa[0] + h[0];
    u32 s = P;
#pragma unroll
    for (int o = 1; o < 64; o <<= 1) {
        u32 vv = __shfl_down(s, o);
        if (lane + o < 64) s += vv;
    }
    const u32 Tex = s - P;

    u32 fA = 0, pkA = 0, fB = 0, pkB = 0;
#pragma unroll
    for (int j = 0; j < 8; ++j) {
        u32 T = Tex + Wa[j];
        u32 e = T + h[j];
        if ((u32)K_BOT >= T && (u32)K_BOT < e)
            { fA = 1; pkA = ((u32)(lane * 8 + j) << 13) | ((u32)K_BOT - T); }
        if ((u32)(K_TOP - 1) >= T && (u32)(K_TOP - 1) < e)
            { fB = 1; pkB = ((u32)(lane * 8 + j) << 13) | ((u32)(K_TOP - 1) - T); }
    }
    {
        u64 mA = __ballot(fA != 0);
        pkA = __shfl(pkA, (int)(__ffsll((unsigned long long)mA) - 1));
        u64 mB = __ballot(fB != 0);
        pkB = __shfl(pkB, (int)(__ffsll((unsigned long long)mB) - 1));
    }
    const u32 binA = pkA >> 13, remA = pkA & 8191u;
    const u32 binB = pkB >> 13, remB = pkB & 8191u;
    const u32 TA = (u32)K_BOT - remA;
    const u32 TB = (u32)(K_TOP - 1) - remB;

    // ---- slot assignment (pure arithmetic) ----
    const float edgeA = unmap16(binA << 7);
    int lo2, topSlots;
    bool fb = false;
    if (edgeA > -1e37f && edgeA < 1e37f) {
        float vt = edgeA - 2.8f;
        int vtBin = (int)((u32)map16(bfbits(vt)) >> 7);
        int binLoSafe = vtBin - 1; if (binLoSafe < 0) binLoSafe = 0;
        int m = (binLoSafe < (int)binA) ? binLoSafe : (int)binA;
        lo2 = ((int)binB + 1 > m) ? (int)binB + 1 : m;
        topSlots = ((int)binA >= lo2) ? ((int)binA - lo2 + 1) : 0;
        if (topSlots + 1 > 8) fb = true;
    } else {
        fb = true;
    }
    if (fb) {                       // fallback: slots only for binB, binA
        lo2 = (int)binA;
        topSlots = ((int)binA > (int)binB) ? 1 : 0;
    }
    const int nslot = topSlots + 1;
    const int sA = topSlots;        // slot of binA (0 when binA==binB)

    // ---- zero sub region, then S2: sub-hist sweep (packed u16 counts) ----
    {
        const uint4 z = make_uint4(0, 0, 0, 0);
#pragma unroll
        for (int i = 0; i < 2; ++i) *(uint4*)&sub[i * 256 + lane * 4] = z;
    }
    // key-space predicate: slotted bins = {binB} U contiguous [lo2..binA]
    const u32 kB0   = (u32)binB << 7;       // binB keys: key-kB0 < 128
    const u32 kL0   = (u32)lo2 << 7;        // contiguous: key-kL0 < spanL
    const u32 spanL = (u32)topSlots << 7;
#pragma unroll 8
    for (int i = 0; i < 16; ++i) {
        uint4 v = rp[i * 64 + lane];
        u32 vv[4] = { v.x, v.y, v.z, v.w };
#pragma unroll
        for (int q = 0; q < 4; ++q) {
#pragma unroll
            for (int hh = 0; hh < 2; ++hh) {
                u32 key = hh ? (vv[q] >> 16) : (vv[q] & 0xFFFFu);
                bool isB = (key - kB0) < 128u;
                bool isL = (key - kL0) < spanL;
                if (isB || isL) {
                    int sl = isB ? 0 : (int)((key >> 7) - (u32)lo2 + 1u);
                    atomicAdd(&sub[sl * 64 + ((key >> 1) & 63u)],
                              (key & 1u) ? 0x10000u : 1u);
                }
            }
        }
    }

    // ---- resolve exact boundary keys + tie counts ----
    u32 idxA, gtA, idxB, gtB;
    resolve_slot(sub, sA, remA, lane, &idxA, &gtA);
    resolve_slot(sub, 0,  remB, lane, &idxB, &gtB);
    const u32 ua = (binA << 7) | idxA;
    const u32 ub = (binB << 7) | idxB;
    const u32 Ga = TA + gtA;
    const u32 Gb = TB + gtB;
    u32 Ea;
    {
        u32 wv = sub[sA * 64 + (idxA >> 1)];
        Ea = (idxA & 1u) ? (wv >> 16) : (wv & 0xFFFFu);
    }

    const float a  = unmap16(ua);
    const float m_ = fmaxf(fmaxf(lp, a), -10.0f) * INV_T;   // exact max

    // ---- window sum ----
    float sm = 0.f;
    if (!fb) {
        for (int ss = 0; ss < nslot; ++ss) {          // wave-uniform
            u32 bs = (ss == 0) ? binB : (u32)(lo2 + ss - 1);
            u32 wv = sub[ss * 64 + lane];
            u32 c0 = wv & 0xFFFFu, c1 = wv >> 16;
            u32 k0 = (bs << 7) | (u32)(lane * 2);
            u32 k1 = k0 | 1u;
            if (c0 && k0 > ub && k0 < ua)
                sm += (float)c0 * __expf(unmap16(k0) * INV_T - m_);
            if (c1 && k1 > ub && k1 < ua)
                sm += (float)c1 * __expf(unmap16(k1) * INV_T - m_);
        }
    } else if (ua != ub) {
        // rare fallback: one extra full sweep with exact m_
        const u32 lo1 = ub + 1u, span = ua - ub - 1u;
#pragma unroll 4
        for (int i = 0; i < 16; ++i) {
            uint4 v = rp[i * 64 + lane];
            u32 vv[4] = { v.x, v.y, v.z, v.w };
#pragma unroll
            for (int q = 0; q < 4; ++q) {
#pragma unroll
                for (int hh = 0; hh < 2; ++hh) {
                    u32 key = hh ? (vv[q] >> 16) : (vv[q] & 0xFFFFu);
                    bool in = (key - lo1) < span;
                    float e = __expf(unmap16(key) * INV_T - m_);
                    sm += in ? e : 0.f;
                }
            }
        }
    }
#pragma unroll
    for (int o = 32; o; o >>= 1) sm += __shfl_down(sm, o);

    if (lane == 0) {
        float bv = unmap16(ub);
        float expA = __expf(a * INV_T - m_);
        float tot;
        if (ua == ub) {
            tot = (float)N_SEL * expA;
        } else {
            float expB = __expf(bv * INV_T - m_);
            tot = sm + (float)(int)(Ga + Ea - (u32)K_BOT) * expA
                     + (float)(int)((u32)K_TOP - Gb) * expB;
        }
        tot += __expf(lp * INV_T - m_) + (float)N_UNSEL * __expf(-10.0f * INV_T - m_);
        loss[row] = m_ + __logf(tot) - lp * INV_T;
    }
}

// ---------------- host ----------------
extern "C" void kernel_launch(void* const* d_in, const int* in_sizes, int n_in,
                              void* d_out, int out_size, void* d_ws, size_t ws_size,
                              hipStream_t stream) {
    const float* fq = (const float*)d_in[0];
    const float* fk = (const float*)d_in[1];
    float* out = (float*)d_out;

    char* ws = (char*)d_ws;
    u16* keys = (u16*)ws;                                  // 128 MiB
    u16* qb = (u16*)(ws + (size_t)NROW * NROW * 2);        // 4 MiB
    u16* kb = qb + (size_t)NROW * NDIM;                    // 4 MiB

    cvt_bf16<<<4096, 256, 0, stream>>>(fq, fk, qb, kb);
    gemm_keys<<<dim3(NROW / 128, NROW / 128), 512, 0, stream>>>(qb, kb, keys);
    rank_lse<<<NROW / 2, 128, 0, stream>>>(keys, fq, fk, out);
}

// Round 18
// 95.813 us; speedup vs baseline: 1.2604x; 1.2604x over previous
//
#include <hip/hip_runtime.h>
#include <hip/hip_bf16.h>

#define NROW 8192
#define NDIM 256
#define INV_T (1.0f / 0.07f)
#define K_BOT 819      // first selected descending rank
#define K_TOP 4095     // one past last selected rank
#define N_SEL 3276
#define N_UNSEL 4916   // 8192 - N_SEL (includes diagonal at -10)

typedef unsigned int u32;
typedef unsigned short u16;
typedef short s16;
typedef unsigned long long u64;
typedef __bf16 bf16_t;
typedef s16 s16x8 __attribute__((ext_vector_type(8)));
typedef float f32x4 __attribute__((ext_vector_type(4)));

__device__ __forceinline__ u16 bfbits(float f) {
    return __builtin_bit_cast(u16, (bf16_t)f);   // RNE f32->bf16, raw bits
}
// order-preserving bf16-bits -> u16 key (bigger float <=> bigger key)
__device__ __forceinline__ u16 map16(u16 b) {
    return (b & 0x8000u) ? (u16)~b : (u16)(b | 0x8000u);
}
__device__ __forceinline__ float unmap16(u32 m) {
    u16 b = (m & 0x8000u) ? (u16)(m & 0x7FFFu) : (u16)~(u16)m;
    return __uint_as_float(((u32)b) << 16);
}

__device__ __forceinline__ void gload16(const void* g, void* l) {
    __builtin_amdgcn_global_load_lds(
        (const __attribute__((address_space(1))) u32*)g,
        (__attribute__((address_space(3))) u32*)l, 16, 0, 0);
}

// ---------------- fp32 -> bf16 (both inputs, one launch) ----------------
__global__ __launch_bounds__(256) void cvt_bf16(const float* __restrict__ in0,
                                                const float* __restrict__ in1,
                                                u16* __restrict__ out0,
                                                u16* __restrict__ out1) {
    int b = blockIdx.x;
    const float* in = (b < 2048) ? in0 : in1;
    u16* out = (b < 2048) ? out0 : out1;
    int i = ((b & 2047) * 256 + threadIdx.x) * 4;
    float4 v = *(const float4*)(in + i);
    ushort4 o;
    o.x = bfbits(v.x); o.y = bfbits(v.y); o.z = bfbits(v.z); o.w = bfbits(v.w);
    *(ushort4*)(out + i) = o;
}

// ---------------- GEMM: keys = map16(bf16(Q @ K^T)) ----------------
// 128x128 tile, BK=64, 8 waves (512 thr), wave tile 64x32 (acc 32 regs).
// Proven round-14 form. No min-waves launch_bounds (round-13 spill lesson).
__global__ __launch_bounds__(512) void gemm_keys(const u16* __restrict__ Qb,
                                                 const u16* __restrict__ Kb,
                                                 u16* __restrict__ Cp) {
    constexpr int BK = 64;
    __shared__ __align__(16) char smem[128 * 132 * 2];   // 33792 B (union)
    u16* sA = (u16*)smem;                    // [128][64] bf16 (16 KB)
    u16* sB = (u16*)(smem + 128 * BK * 2);   // [128][64] (16 KB)
    u16* sC = (u16*)smem;                    // [128][132] epilogue transpose

    const int tid  = threadIdx.x;
    const int lane = tid & 63;
    const int wid  = tid >> 6;               // 0..7
    const int wr = wid & 1;                  // row half   (64 rows)
    const int wc = wid >> 1;                 // col quarter (32 cols)
    const int bm = blockIdx.y * 128;
    const int bn = blockIdx.x * 128;
    const int kg = lane >> 4;
    const int fr = lane & 15;

    // staging: segment = 8 rows x 128B; lane l -> row seg*8 + (l>>3),
    // LDS chunk jp = l&7 holds source chunk j = jp ^ (row&7).
    const int srr = lane >> 3;
    const int srj = (lane & 7) ^ srr;

    f32x4 acc[4][2] = {};

    for (int k0 = 0; k0 < NDIM; k0 += BK) {
        __syncthreads();
#pragma unroll
        for (int s = 0; s < 2; ++s) {
            int seg = wid * 2 + s;               // 0..15
            int row = seg * 8 + srr;
            gload16(Qb + (size_t)(bm + row) * NDIM + k0 + srj * 8, &sA[seg * 512]);
            gload16(Kb + (size_t)(bn + row) * NDIM + k0 + srj * 8, &sB[seg * 512]);
        }
        __syncthreads();

#pragma unroll
        for (int kk = 0; kk < 2; ++kk) {
            s16x8 af[4], bfv[2];
            const int jp = (kk * 4 + kg) ^ (fr & 7);   // row&7 == fr&7 below
#pragma unroll
            for (int m = 0; m < 4; ++m) {
                int row = wr * 64 + m * 16 + fr;
                af[m] = *(const s16x8*)(&sA[row * BK + jp * 8]);
            }
#pragma unroll
            for (int n = 0; n < 2; ++n) {
                int row = wc * 32 + n * 16 + fr;
                bfv[n] = *(const s16x8*)(&sB[row * BK + jp * 8]);
            }
#pragma unroll
            for (int m = 0; m < 4; ++m)
#pragma unroll
                for (int n = 0; n < 2; ++n)
                    acc[m][n] = __builtin_amdgcn_mfma_f32_16x16x32_bf16(
                        af[m], bfv[n], acc[m][n], 0, 0, 0);
        }
    }

    __syncthreads();   // done reading sA/sB; reuse LDS as sC
#pragma unroll
    for (int m = 0; m < 4; ++m)
#pragma unroll
        for (int n = 0; n < 2; ++n)
#pragma unroll
            for (int jj = 0; jj < 4; ++jj) {
                int r = wr * 64 + m * 16 + kg * 4 + jj;   // C/D: row=(lane>>4)*4+reg
                int c = wc * 32 + n * 16 + fr;            //      col=lane&15
                sC[r * 132 + c] = map16(bfbits(acc[m][n][jj]));
            }
    __syncthreads();
    if (bm == bn) {
        if (tid < 128) sC[tid * 132 + tid] = 0;   // diagonal sentinel (unique min)
        __syncthreads();
    }
#pragma unroll
    for (int it = 0; it < 4; ++it) {
        int idx = it * 512 + tid;                 // 0..2047 16B chunks
        int row = idx >> 4, col8 = (idx & 15) * 8;
        *(uint4*)(&Cp[(size_t)(bm + row) * NROW + bn + col8]) =
            *(const uint4*)(&sC[row * 132 + col8]);
    }
}

// ---------------- wave helpers ----------------
__device__ __forceinline__ u32 wave_sum_u32(u32 x) {
#pragma unroll
    for (int o = 32; o; o >>= 1) x += __shfl_down(x, o);
    return __shfl(x, 0);
}

// resolve rank `rem` within a 128-key sub-hist (packed u16 counts, 64 words)
__device__ __forceinline__ void resolve_slot(const u32* sub, int slot, u32 rem,
                                             int lane, u32* idxOut, u32* gtOut) {
    u32 word = sub[slot * 64 + lane];
    u32 c0 = word & 0xFFFFu, c1 = word >> 16;     // idx 2*lane, 2*lane+1
    u32 s0 = c0 + c1, suf = s0;
#pragma unroll
    for (int o = 1; o < 64; o <<= 1) {
        u32 v = __shfl_down(suf, o);
        if (lane + o < 64) suf += v;
    }
    u32 TexL = suf - s0;                  // counts in higher lanes
    u32 f = 0, pk = 0;
    u32 ab0 = TexL + c1;                  // keys above idx 2*lane
    if (rem >= ab0 && rem < ab0 + c0) { f = 1; pk = ((u32)(lane * 2) << 16) | ab0; }
    if (rem >= TexL && rem < TexL + c1) { f = 1; pk = ((u32)(lane * 2 + 1) << 16) | TexL; }
    u64 mm = __ballot(f != 0);
    pk = __shfl(pk, (int)(__ffsll((unsigned long long)mm) - 1));
    *idxOut = pk >> 16;
    *gtOut = pk & 0xFFFFu;
}

// full-row bisect via global re-sweeps (pathological fallback only)
__device__ u32 bisect_row(const uint4* rp, u32 rank, int lane) {
    u32 lo = 0, hi = 65535;
    while (lo < hi) {
        u32 mid = (lo + hi) >> 1;
        u32 pc = 0;
        for (int i = 0; i < 16; ++i) {
            uint4 v = rp[i * 64 + lane];
            pc += (u32)((v.x & 0xFFFFu) > mid) + (u32)((v.x >> 16) > mid)
                + (u32)((v.y & 0xFFFFu) > mid) + (u32)((v.y >> 16) > mid)
                + (u32)((v.z & 0xFFFFu) > mid) + (u32)((v.z >> 16) > mid)
                + (u32)((v.w & 0xFFFFu) > mid) + (u32)((v.w >> 16) > mid);
        }
        u32 c = wave_sum_u32(pc);
        if (c <= rank) hi = mid; else lo = mid + 1;
    }
    return lo;
}

// ---------------- rank select + LSE: 1 wave/row, 0 barriers, ONE sweep ----
// Speculative range R = values [8,64) (keys [0xC100,0xC280), 3 x 128-key
// slots). Numerics: with T=0.07, terms >2.8 below the window max vanish
// (<e^-40). If rank-819 in R, rank-4094 below R, and a >= 10.9 (all verified
// from exact counts), the dropped terms are < 1e-15 relative -> fp32-exact.
// Any violation -> exact full-row bisect fallback (never for benign data).
#define KLO 0xC100u     // key of value 8.0
#define KHI 0xC280u     // key of value 64.0
#define RSPAN 0x180u    // 384 keys, 3 slots
#define NSLOT 3

__global__ __launch_bounds__(128, 8) void rank_lse(const u16* __restrict__ Cp,
                                                   const float* __restrict__ fq,
                                                   const float* __restrict__ fk,
                                                   float* __restrict__ loss) {
    __shared__ u32 lds_s[2][NSLOT * 64];  // 1.5 KB/block; per-wave private
    const int t = threadIdx.x;
    const int w = t >> 6;
    const int lane = t & 63;
    const int row = blockIdx.x * 2 + w;

    u32* sub = lds_s[w];
    const uint4* rp = (const uint4*)(Cp + (size_t)row * NROW);

    // zero sub-hists (192 words)
    if (lane < 48) *(uint4*)&sub[lane * 4] = make_uint4(0, 0, 0, 0);

    // exact fp32 l_pos
    float lp;
    {
        float4 q4 = *(const float4*)(fq + (size_t)row * NDIM + lane * 4);
        float4 k4 = *(const float4*)(fk + (size_t)row * NDIM + lane * 4);
        float p = q4.x * k4.x + q4.y * k4.y + q4.z * k4.z + q4.w * k4.w;
#pragma unroll
        for (int o = 32; o; o >>= 1) p += __shfl_down(p, o);
        lp = __shfl(p, 0);
    }

    // ---- single sweep: count-above-R + sub-hist R keys ----
    u32 cntHi = 0;
#pragma unroll 4
    for (int i = 0; i < 16; ++i) {
        uint4 v = rp[i * 64 + lane];
        u32 vv[4] = { v.x, v.y, v.z, v.w };
#pragma unroll
        for (int q = 0; q < 4; ++q) {
#pragma unroll
            for (int hh = 0; hh < 2; ++hh) {
                u32 key = hh ? (vv[q] >> 16) : (vv[q] & 0xFFFFu);
                cntHi += (key >= KHI) ? 1u : 0u;
                u32 d = key - KLO;
                if (d < RSPAN)
                    atomicAdd(&sub[(d >> 7) * 64 + ((key >> 1) & 63u)],
                              (key & 1u) ? 0x10000u : 1u);
            }
        }
    }
    const u32 CH = wave_sum_u32(cntHi);

    // ---- slot totals (packed reduce) ----
    u32 T0, T1, T2;
    {
        u32 w0 = sub[lane], w1 = sub[64 + lane], w2 = sub[128 + lane];
        u32 m0 = (w0 & 0xFFFFu) + (w0 >> 16);
        u32 m1 = (w1 & 0xFFFFu) + (w1 >> 16);
        u32 m2 = (w2 & 0xFFFFu) + (w2 >> 16);
        u32 p01 = wave_sum_u32(m0 | (m1 << 16));
        T2 = wave_sum_u32(m2);
        T0 = p01 & 0xFFFFu; T1 = p01 >> 16;
    }
    const u32 NR = T0 + T1 + T2;

    bool fb = !((CH <= (u32)K_BOT) && ((u32)K_BOT < CH + NR))
            || ((u32)(K_TOP - 1) < CH + NR);

    u32 ua = 0, Ga = 0, Ea = 0;
    float a = 0.f;
    int sA = 0;
    if (!fb) {
        // locate slot of rank K_BOT (slot 2 = highest values)
        const u32 AT2 = CH, AT1 = CH + T2, AT0 = AT1 + T1;
        u32 ATA;
        if ((u32)K_BOT >= AT0)      { sA = 0; ATA = AT0; }
        else if ((u32)K_BOT >= AT1) { sA = 1; ATA = AT1; }
        else                        { sA = 2; ATA = AT2; }
        const u32 remA = (u32)K_BOT - ATA;
        u32 idxA, gtA;
        resolve_slot(sub, sA, remA, lane, &idxA, &gtA);
        ua = KLO + ((u32)sA << 7) + idxA;
        Ga = ATA + gtA;
        {
            u32 wv = sub[sA * 64 + (idxA >> 1)];
            Ea = (idxA & 1u) ? (wv >> 16) : (wv & 0xFFFFu);
        }
        a = unmap16(ua);
        if (!(a >= 10.9f)) fb = true;   // significance guard for dropped terms
    }

    if (!fb) {
        // ---- fast epilogue: everything from sub-hists ----
        const float m_ = fmaxf(fmaxf(lp, a), -10.0f) * INV_T;
        float sm = 0.f;
#pragma unroll
        for (int s = 0; s < NSLOT; ++s) {
            u32 wv = sub[s * 64 + lane];
            u32 c0 = wv & 0xFFFFu, c1 = wv >> 16;
            u32 k0 = KLO + ((u32)s << 7) + (u32)(lane * 2);
            u32 k1 = k0 | 1u;
            if (c0 && k0 < ua) sm += (float)c0 * __expf(unmap16(k0) * INV_T - m_);
            if (c1 && k1 < ua) sm += (float)c1 * __expf(unmap16(k1) * INV_T - m_);
        }
#pragma unroll
        for (int o = 32; o; o >>= 1) sm += __shfl_down(sm, o);
        if (lane == 0) {
            float expA = __expf(a * INV_T - m_);
            float tot = sm + (float)(int)(Ga + Ea - (u32)K_BOT) * expA;
            // B-side & sub-R terms provably < 1e-15 relative: omitted
            tot += __expf(lp * INV_T - m_)
                 + (float)N_UNSEL * __expf(-10.0f * INV_T - m_);
            loss[row] = m_ + __logf(tot) - lp * INV_T;
        }
    } else {
        // ---- exact fallback: full-row bisects + tie-exact sweep ----
        u32 fua = bisect_row(rp, (u32)K_BOT, lane);
        u32 fub = bisect_row(rp, (u32)(K_TOP - 1), lane);
        float fa = unmap16(fua);
        const float m_ = fmaxf(fmaxf(lp, fa), -10.0f) * INV_T;
        u32 cga = 0, cea = 0, cgb = 0;
        float sm = 0.f;
        for (int i = 0; i < 16; ++i) {
            uint4 v = rp[i * 64 + lane];
            u32 vv[4] = { v.x, v.y, v.z, v.w };
#pragma unroll
            for (int q = 0; q < 4; ++q) {
#pragma unroll
                for (int hh = 0; hh < 2; ++hh) {
                    u32 u = hh ? (vv[q] >> 16) : (vv[q] & 0xFFFFu);
                    cga += (u > fua); cea += (u == fua); cgb += (u > fub);
                    if (u > fub && u < fua)
                        sm += __expf(unmap16(u) * INV_T - m_);
                }
            }
        }
        u32 fGa = wave_sum_u32(cga), fEa = wave_sum_u32(cea), fGb = wave_sum_u32(cgb);
#pragma unroll
        for (int o = 32; o; o >>= 1) sm += __shfl_down(sm, o);
        if (lane == 0) {
            float bv = unmap16(fub);
            float expA = __expf(fa * INV_T - m_);
            float tot;
            if (fua == fub) {
                tot = (float)N_SEL * expA;
            } else {
                float expB = __expf(bv * INV_T - m_);
                tot = sm + (float)(int)(fGa + fEa - (u32)K_BOT) * expA
                         + (float)(int)((u32)K_TOP - fGb) * expB;
            }
            tot += __expf(lp * INV_T - m_)
                 + (float)N_UNSEL * __expf(-10.0f * INV_T - m_);
            loss[row] = m_ + __logf(tot) - lp * INV_T;
        }
    }
}

// ---------------- host ----------------
extern "C" void kernel_launch(void* const* d_in, const int* in_sizes, int n_in,
                              void* d_out, int out_size, void* d_ws, size_t ws_size,
                              hipStream_t stream) {
    const float* fq = (const float*)d_in[0];
    const float* fk = (const float*)d_in[1];
    float* out = (float*)d_out;

    char* ws = (char*)d_ws;
    u16* keys = (u16*)ws;                                  // 128 MiB
    u16* qb = (u16*)(ws + (size_t)NROW * NROW * 2);        // 4 MiB
    u16* kb = qb + (size_t)NROW * NDIM;                    // 4 MiB

    cvt_bf16<<<4096, 256, 0, stream>>>(fq, fk, qb, kb);
    gemm_keys<<<dim3(NROW / 128, NROW / 128), 512, 0, stream>>>(qb, kb, keys);
    rank_lse<<<NROW / 2, 128, 0, stream>>>(keys, fq, fk, out);
}